// Round 6
// baseline (163.224 us; speedup 1.0000x reference)
//
#include <hip/hip_runtime.h>
#include <hip/hip_cooperative_groups.h>
#include <math.h>
#include <float.h>

namespace cg = cooperative_groups;

#define B_ 32
#define N_ 256
#define T_OBS_ 50
#define T_S_ 25
#define D_ 128
#define D_H_ 256
#define P_ 8
#define NCH_ 8                // n-chunks per batch in phase 1
#define NPC_ (N_ / NCH_)      // 32 n per chunk
#define PLANE_ (T_S_ * D_)    // 3200 floats per (b,n)
#define RB_ 4                 // rows per block in phase 2
#define NBLK_ 256
#define THREADS_ 800
#define MBLK_ 200             // blocks doing phase 2

static constexpr double TWO_PI_D = 6.283185307179586476925286766559;
static constexpr float EPS_F = 1e-4f;

// ---------------------------------------------------------------------------
// Single cooperative kernel.
// Phase 1 (all 256 blocks): R5's K1 byte-identical math — block (b, c) streams
// a contiguous 409.6 KB of f_nei, thread owns one float4 of the (t,d) plane,
// max-reduces 32 n; writes partials to ws.
// grid.sync()
// Phase 2 (blocks 0..199): R5's float4 MLP with RB_=4 rows/block + histogram
// + output. Work guarded to thread subsets; barriers unconditional.
// ---------------------------------------------------------------------------
__global__ __launch_bounds__(THREADS_) void fused_all(
    const float* __restrict__ f_ego, const float* __restrict__ f_nei,
    float* __restrict__ part, const float* __restrict__ W1,
    const float* __restrict__ b1, const float* __restrict__ W2,
    const float* __restrict__ b2, const float* __restrict__ W3,
    const float* __restrict__ b3, const float* __restrict__ x_ego,
    const float* __restrict__ x_nei, const float* __restrict__ Wce,
    const float* __restrict__ bce, float* __restrict__ out) {
  __shared__ float spool[8192];      // 32 KB k-slice partial pool
  __shared__ float sin_[RB_][D_];    // 2 KB
  __shared__ float sh1[RB_][D_H_];   // 4 KB
  __shared__ float sh2[RB_][D_H_];   // 4 KB
  __shared__ float f3s[RB_][64];     // 1 KB
  __shared__ float cnt[RB_][P_], dsum[RB_][P_], asum[RB_][P_];

  const int tid = threadIdx.x;
  const int bid = blockIdx.x;

  // ======================= phase 1: n-chunk max =======================
  {
    int b = bid >> 3, c = bid & 7;
    int t = tid >> 5, d4 = tid & 31;
    const float4 e =
        *(const float4*)(f_ego + ((size_t)b * T_S_ + t) * D_ + 4 * d4);
    const float* base =
        f_nei + ((size_t)b * N_ + (size_t)c * NPC_) * PLANE_ + 4 * tid;
    float4 m = make_float4(-FLT_MAX, -FLT_MAX, -FLT_MAX, -FLT_MAX);
#pragma unroll 8
    for (int i = 0; i < NPC_; ++i) {
      float4 v = *(const float4*)(base + (size_t)i * PLANE_);
      m.x = fmaxf(m.x, e.x * v.x);
      m.y = fmaxf(m.y, e.y * v.y);
      m.z = fmaxf(m.z, e.z * v.z);
      m.w = fmaxf(m.w, e.w * v.w);
    }
    *(float4*)(part + (size_t)bid * PLANE_ + 4 * tid) = m;
  }
  __threadfence();
  cg::this_grid().sync();
  if (bid >= MBLK_) return;

  // ======================= phase 2: MLP + histogram + output ==========
  const int row0 = bid * RB_;

  if (tid < RB_ * P_) {
    (&cnt[0][0])[tid] = 0.f;
    (&dsum[0][0])[tid] = 0.f;
    (&asum[0][0])[tid] = 0.f;
  }

  // combine phase-1 partials -> sin_ (RB_*128 = 512 values)
  if (tid < RB_ * D_) {
    int r = tid >> 7, d = tid & 127;
    int row = row0 + r;
    int b = row / T_S_, t = row - b * T_S_;
    const float* pp = part + (size_t)b * NCH_ * PLANE_ + t * D_ + d;
    float m = -FLT_MAX;
#pragma unroll
    for (int c = 0; c < NCH_; ++c) m = fmaxf(m, pp[(size_t)c * PLANE_]);
    sin_[r][d] = m;
  }

  // histogram input loads, hoisted. items = RB_*256 = 1024; thread does
  // item tid and (if tid<224) item tid+800. Static slots (no dyn indexing).
  float2 eg0, xn0, eg1, xn1;
  {
    int r = tid >> 8, n = tid & 255;
    int row = row0 + r;
    int b = row / T_S_, t = row - b * T_S_;
    int tobs = 2 * t;
    eg0 = *(const float2*)&x_ego[((size_t)b * T_OBS_ + tobs) * 2];
    xn0 = *(const float2*)&x_nei[(((size_t)b * N_ + n) * T_OBS_ + tobs) * 2];
  }
  const bool has1 = (tid < RB_ * 256 - THREADS_);  // tid < 224
  if (has1) {
    int i = tid + THREADS_;
    int r = i >> 8, n = i & 255;
    int row = row0 + r;
    int b = row / T_S_, t = row - b * T_S_;
    int tobs = 2 * t;
    eg1 = *(const float2*)&x_ego[((size_t)b * T_OBS_ + tobs) * 2];
    xn1 = *(const float2*)&x_nei[(((size_t)b * N_ + n) * T_OBS_ + tobs) * 2];
  }
  __syncthreads();  // B1: sin_ ready

  // ---- layer 1: 128 -> 256. tid<512: s=tid>>6 (8 slices of 16 k), j4 ----
  if (tid < 512) {
    const int s = tid >> 6, j4 = tid & 63;
    const float4* W1v = (const float4*)W1;
    float a[RB_][4] = {};
#pragma unroll
    for (int kk = 0; kk < 16; ++kk) {
      int k = s * 16 + kk;
      float4 w = W1v[k * 64 + j4];
#pragma unroll
      for (int r = 0; r < RB_; ++r) {
        float x = sin_[r][k];
        a[r][0] = fmaf(x, w.x, a[r][0]);
        a[r][1] = fmaf(x, w.y, a[r][1]);
        a[r][2] = fmaf(x, w.z, a[r][2]);
        a[r][3] = fmaf(x, w.w, a[r][3]);
      }
    }
#pragma unroll
    for (int r = 0; r < RB_; ++r)
      *(float4*)&spool[(s * RB_ + r) * 256 + 4 * j4] =
          make_float4(a[r][0], a[r][1], a[r][2], a[r][3]);
  }
  __syncthreads();  // B2
  {  // combine1: 1024 values, items tid and tid+800
    int r = tid >> 8, j = tid & 255;
    float sum = b1[j];
#pragma unroll
    for (int s = 0; s < 8; ++s) sum += spool[(s * RB_ + r) * 256 + j];
    sh1[r][j] = fmaxf(sum, 0.f);
    if (has1) {
      int i = tid + THREADS_;
      int r2 = i >> 8, j2 = i & 255;
      float sum2 = b1[j2];
#pragma unroll
      for (int s = 0; s < 8; ++s) sum2 += spool[(s * RB_ + r2) * 256 + j2];
      sh1[r2][j2] = fmaxf(sum2, 0.f);
    }
  }
  __syncthreads();  // B3: sh1 ready

  // ---- layer 2: 256 -> 256. tid<512: 8 slices of 32 k ----
  if (tid < 512) {
    const int s = tid >> 6, j4 = tid & 63;
    const float4* W2v = (const float4*)W2;
    float a[RB_][4] = {};
#pragma unroll
    for (int kk = 0; kk < 32; ++kk) {
      int k = s * 32 + kk;
      float4 w = W2v[k * 64 + j4];
#pragma unroll
      for (int r = 0; r < RB_; ++r) {
        float x = sh1[r][k];
        a[r][0] = fmaf(x, w.x, a[r][0]);
        a[r][1] = fmaf(x, w.y, a[r][1]);
        a[r][2] = fmaf(x, w.z, a[r][2]);
        a[r][3] = fmaf(x, w.w, a[r][3]);
      }
    }
#pragma unroll
    for (int r = 0; r < RB_; ++r)
      *(float4*)&spool[(s * RB_ + r) * 256 + 4 * j4] =
          make_float4(a[r][0], a[r][1], a[r][2], a[r][3]);
  }
  __syncthreads();  // B4
  {  // combine2
    int r = tid >> 8, j = tid & 255;
    float sum = b2[j];
#pragma unroll
    for (int s = 0; s < 8; ++s) sum += spool[(s * RB_ + r) * 256 + j];
    sh2[r][j] = fmaxf(sum, 0.f);
    if (has1) {
      int i = tid + THREADS_;
      int r2 = i >> 8, j2 = i & 255;
      float sum2 = b2[j2];
#pragma unroll
      for (int s = 0; s < 8; ++s) sum2 += spool[(s * RB_ + r2) * 256 + j2];
      sh2[r2][j2] = fmaxf(sum2, 0.f);
    }
  }
  __syncthreads();  // B5: sh2 ready, spool free

  // ---- layer 3: 256 -> 64. tid<512: s3=tid>>4 (32 slices of 8 k) ----
  if (tid < 512) {
    const int s3 = tid >> 4, j4 = tid & 15;
    const float4* W3v = (const float4*)W3;
    float a[RB_][4] = {};
#pragma unroll
    for (int kk = 0; kk < 8; ++kk) {
      int k = s3 * 8 + kk;
      float4 w = W3v[k * 16 + j4];
#pragma unroll
      for (int r = 0; r < RB_; ++r) {
        float x = sh2[r][k];
        a[r][0] = fmaf(x, w.x, a[r][0]);
        a[r][1] = fmaf(x, w.y, a[r][1]);
        a[r][2] = fmaf(x, w.z, a[r][2]);
        a[r][3] = fmaf(x, w.w, a[r][3]);
      }
    }
#pragma unroll
    for (int r = 0; r < RB_; ++r)
      *(float4*)&spool[(s3 * RB_ + r) * 64 + 4 * j4] =
          make_float4(a[r][0], a[r][1], a[r][2], a[r][3]);
  }
  // ---- histogram math + LDS atomics (independent of layer 3) ----
  {
    int r = tid >> 8;
    float p0 = xn0.x - eg0.x;
    float p1 = xn0.y - eg0.y;
    float dist = sqrtf(p0 * p0 + p1 * p1);
    double angd = atan2((double)p0, (double)p1);
    if (angd < 0.0) angd += TWO_PI_D;
    float ang = (float)angd;
    int pidx = (int)(angd / (TWO_PI_D / (double)P_));
    bool mask = ((fabsf(p0) + fabsf(p1)) != 0.f) && (dist > 0.005f);
    if (mask && pidx >= 0 && pidx < P_) {
      atomicAdd(&cnt[r][pidx], 1.f);
      atomicAdd(&dsum[r][pidx], dist);
      atomicAdd(&asum[r][pidx], ang);
    }
    if (has1) {
      int r2 = (tid + THREADS_) >> 8;
      float q0 = xn1.x - eg1.x;
      float q1 = xn1.y - eg1.y;
      float dist2 = sqrtf(q0 * q0 + q1 * q1);
      double angd2 = atan2((double)q0, (double)q1);
      if (angd2 < 0.0) angd2 += TWO_PI_D;
      float ang2 = (float)angd2;
      int pidx2 = (int)(angd2 / (TWO_PI_D / (double)P_));
      bool mask2 = ((fabsf(q0) + fabsf(q1)) != 0.f) && (dist2 > 0.005f);
      if (mask2 && pidx2 >= 0 && pidx2 < P_) {
        atomicAdd(&cnt[r2][pidx2], 1.f);
        atomicAdd(&dsum[r2][pidx2], dist2);
        atomicAdd(&asum[r2][pidx2], ang2);
      }
    }
  }
  __syncthreads();  // B6: layer3 partials + histogram done

  if (tid < RB_ * 64) {  // 256
    int r = tid >> 6, j = tid & 63;
    float sum = b3[j];
#pragma unroll
    for (int s = 0; s < 32; ++s) sum += spool[(s * RB_ + r) * 64 + j];
    f3s[r][j] = fmaxf(sum, 0.f);
  }
  __syncthreads();  // B7: f3s ready

  // ---- output: RB_ rows x 1024 floats = 1024 float4; items tid, tid+800 ----
  {
    int i = tid;
    int r = i >> 8, i4 = i & 255;
    int p = i4 >> 5, c0 = (i4 & 31) * 4;
    float nn = cnt[r][p] + EPS_F;
    float4 v;
    if (c0 < 64) {
      float sc = cnt[r][p] / nn;
      v = make_float4(f3s[r][c0 + 0] * sc, f3s[r][c0 + 1] * sc,
                      f3s[r][c0 + 2] * sc, f3s[r][c0 + 3] * sc);
    } else {
      int jj = c0 - 64;
      float dm = dsum[r][p] / nn, am = asum[r][p] / nn;
      v.x = fmaxf(fmaf(dm, Wce[jj + 0], fmaf(am, Wce[64 + jj + 0], bce[jj + 0])), 0.f);
      v.y = fmaxf(fmaf(dm, Wce[jj + 1], fmaf(am, Wce[64 + jj + 1], bce[jj + 1])), 0.f);
      v.z = fmaxf(fmaf(dm, Wce[jj + 2], fmaf(am, Wce[64 + jj + 2], bce[jj + 2])), 0.f);
      v.w = fmaxf(fmaf(dm, Wce[jj + 3], fmaf(am, Wce[64 + jj + 3], bce[jj + 3])), 0.f);
    }
    *(float4*)(out + (size_t)(row0 + r) * 1024 + 4 * i4) = v;
    if (has1) {
      int i2 = tid + THREADS_;
      int r2 = i2 >> 8, i42 = i2 & 255;
      int p2 = i42 >> 5, c02 = (i42 & 31) * 4;
      float nn2 = cnt[r2][p2] + EPS_F;
      float4 v2;
      if (c02 < 64) {
        float sc = cnt[r2][p2] / nn2;
        v2 = make_float4(f3s[r2][c02 + 0] * sc, f3s[r2][c02 + 1] * sc,
                         f3s[r2][c02 + 2] * sc, f3s[r2][c02 + 3] * sc);
      } else {
        int jj = c02 - 64;
        float dm = dsum[r2][p2] / nn2, am = asum[r2][p2] / nn2;
        v2.x = fmaxf(fmaf(dm, Wce[jj + 0], fmaf(am, Wce[64 + jj + 0], bce[jj + 0])), 0.f);
        v2.y = fmaxf(fmaf(dm, Wce[jj + 1], fmaf(am, Wce[64 + jj + 1], bce[jj + 1])), 0.f);
        v2.z = fmaxf(fmaf(dm, Wce[jj + 2], fmaf(am, Wce[64 + jj + 2], bce[jj + 2])), 0.f);
        v2.w = fmaxf(fmaf(dm, Wce[jj + 3], fmaf(am, Wce[64 + jj + 3], bce[jj + 3])), 0.f);
      }
      *(float4*)(out + (size_t)(row0 + r2) * 1024 + 4 * i42) = v2;
    }
  }
}

// ---------------------------------------------------------------------------
extern "C" void kernel_launch(void* const* d_in, const int* in_sizes, int n_in,
                              void* d_out, int out_size, void* d_ws,
                              size_t ws_size, hipStream_t stream) {
  const float* x_ego = (const float*)d_in[0];   // (32,50,2)
  const float* x_nei = (const float*)d_in[1];   // (32,256,50,2)
  const float* f_ego = (const float*)d_in[2];   // (32,25,128)
  const float* f_nei = (const float*)d_in[3];   // (32,256,25,128)
  const float* W1 = (const float*)d_in[4];      // (128,256)
  const float* b1 = (const float*)d_in[5];
  const float* W2 = (const float*)d_in[6];      // (256,256)
  const float* b2 = (const float*)d_in[7];
  const float* W3 = (const float*)d_in[8];      // (256,64)
  const float* b3 = (const float*)d_in[9];
  const float* Wce = (const float*)d_in[10];    // (2,64)
  const float* bce = (const float*)d_in[11];
  float* out = (float*)d_out;                   // (32,25,8,128)

  float* part = (float*)d_ws;  // 256 * 3200 floats = 3.28 MB

  void* kargs[] = {(void*)&f_ego, (void*)&f_nei, (void*)&part,
                   (void*)&W1,    (void*)&b1,    (void*)&W2,
                   (void*)&b2,    (void*)&W3,    (void*)&b3,
                   (void*)&x_ego, (void*)&x_nei, (void*)&Wce,
                   (void*)&bce,   (void*)&out};
  hipLaunchCooperativeKernel(reinterpret_cast<const void*>(&fused_all),
                             dim3(NBLK_), dim3(THREADS_), kargs, 0, stream);
}

// Round 7
// 39.202 us; speedup vs baseline: 4.1636x; 4.1636x over previous
//
#include <hip/hip_runtime.h>
#include <math.h>
#include <float.h>

#define B_ 32
#define N_ 256
#define T_OBS_ 50
#define T_S_ 25
#define D_ 128
#define D_H_ 256
#define P_ 8
#define NCH_ 16               // n-chunks in K1 (512 blocks = 2/CU)
#define NPC_ (N_ / NCH_)      // 16 n per chunk
#define PLANE_ (T_S_ * D_)    // 3200 floats per (b,n)
#define RB_ 2                 // rows per block in K2

static constexpr double TWO_PI_D = 6.283185307179586476925286766559;
static constexpr float EPS_F = 1e-4f;

// ---------------------------------------------------------------------------
// K1: partial max over an n-chunk, contiguous streaming. 512 blocks (2/CU),
// 800 threads, fully unrolled 16 in-flight float4 loads per thread to cover
// L3 hit latency (f_nei is L3-resident across replays — R6 profile).
// ---------------------------------------------------------------------------
__global__ __launch_bounds__(800) void k1_partial(
    const float* __restrict__ f_ego, const float* __restrict__ f_nei,
    float* __restrict__ part) {
  int b = blockIdx.x >> 4;
  int c = blockIdx.x & 15;
  int tid = threadIdx.x;  // 0..799
  int t = tid >> 5;
  int d4 = tid & 31;

  const float4 e =
      *(const float4*)(f_ego + ((size_t)b * T_S_ + t) * D_ + 4 * d4);
  const float* base =
      f_nei + ((size_t)b * N_ + (size_t)c * NPC_) * PLANE_ + 4 * tid;

  float4 m = make_float4(-FLT_MAX, -FLT_MAX, -FLT_MAX, -FLT_MAX);
#pragma unroll 16
  for (int i = 0; i < NPC_; ++i) {
    float4 v = *(const float4*)(base + (size_t)i * PLANE_);
    m.x = fmaxf(m.x, e.x * v.x);
    m.y = fmaxf(m.y, e.y * v.y);
    m.z = fmaxf(m.z, e.z * v.z);
    m.w = fmaxf(m.w, e.w * v.w);
  }
  *(float4*)(part + (size_t)blockIdx.x * PLANE_ + 4 * tid) = m;
}

// ---------------------------------------------------------------------------
// K2: fused combine + MLP + polar histogram + output (R5 winner, unchanged
// except combine loop now spans 16 chunks). 400 blocks x 512 threads.
// ---------------------------------------------------------------------------
__global__ __launch_bounds__(512) void k2_fused(
    const float* __restrict__ part, const float* __restrict__ W1,
    const float* __restrict__ b1, const float* __restrict__ W2,
    const float* __restrict__ b2, const float* __restrict__ W3,
    const float* __restrict__ b3, const float* __restrict__ x_ego,
    const float* __restrict__ x_nei, const float* __restrict__ Wce,
    const float* __restrict__ bce, float* __restrict__ out) {
  __shared__ float spool[4096];     // 16 KB k-slice partials
  __shared__ float sin_[RB_][D_];   // 1 KB
  __shared__ float sh1[RB_][D_H_];  // 2 KB
  __shared__ float sh2[RB_][D_H_];  // 2 KB
  __shared__ float f3s[RB_][64];
  __shared__ float cnt[RB_][P_], dsum[RB_][P_], asum[RB_][P_];

  const int tid = threadIdx.x;
  const int row0 = blockIdx.x * RB_;

  if (tid < RB_ * P_) {
    (&cnt[0][0])[tid] = 0.f;
    (&dsum[0][0])[tid] = 0.f;
    (&asum[0][0])[tid] = 0.f;
  }

  // ---- combine K1 partials -> sin_ (256 values, 1 per thread) ----
  if (tid < RB_ * D_) {
    int r = tid >> 7, d = tid & 127;
    int row = row0 + r;
    int b = row / T_S_, t = row - b * T_S_;
    const float* p = part + (size_t)b * NCH_ * PLANE_ + t * D_ + d;
    float m = -FLT_MAX;
#pragma unroll
    for (int c = 0; c < NCH_; ++c) m = fmaxf(m, p[(size_t)c * PLANE_]);
    sin_[r][d] = m;
  }

  // ---- histogram input loads, hoisted (1 item per thread) ----
  float2 eg, xn;
  {
    int r = tid >> 8, n = tid & 255;
    int row = row0 + r;
    int b = row / T_S_, t = row - b * T_S_;
    int tobs = 2 * t;
    eg = *(const float2*)&x_ego[((size_t)b * T_OBS_ + tobs) * 2];
    xn = *(const float2*)&x_nei[(((size_t)b * N_ + n) * T_OBS_ + tobs) * 2];
  }

  const float bb1 = b1[tid & 255];
  const float bb2 = b2[tid & 255];

  __syncthreads();  // B1: sin_ ready

  // ---- layer 1: 128 -> 256. s=tid>>6 (8 slices of 16 k), j4=tid&63 ----
  {
    const int s = tid >> 6, j4 = tid & 63;
    const float4* W1v = (const float4*)W1;
    float a[RB_][4] = {};
#pragma unroll
    for (int kk = 0; kk < 16; ++kk) {
      int k = s * 16 + kk;
      float4 w = W1v[k * 64 + j4];
#pragma unroll
      for (int r = 0; r < RB_; ++r) {
        float x = sin_[r][k];
        a[r][0] = fmaf(x, w.x, a[r][0]);
        a[r][1] = fmaf(x, w.y, a[r][1]);
        a[r][2] = fmaf(x, w.z, a[r][2]);
        a[r][3] = fmaf(x, w.w, a[r][3]);
      }
    }
#pragma unroll
    for (int r = 0; r < RB_; ++r)
      *(float4*)&spool[(s * RB_ + r) * 256 + 4 * j4] =
          make_float4(a[r][0], a[r][1], a[r][2], a[r][3]);
  }
  __syncthreads();  // B2
  {
    int r = tid >> 8, j = tid & 255;
    float sum = bb1;
#pragma unroll
    for (int s = 0; s < 8; ++s) sum += spool[(s * RB_ + r) * 256 + j];
    sh1[r][j] = fmaxf(sum, 0.f);
  }
  __syncthreads();  // B3: sh1 ready

  // ---- layer 2: 256 -> 256. s: 8 slices of 32 k ----
  {
    const int s = tid >> 6, j4 = tid & 63;
    const float4* W2v = (const float4*)W2;
    float a[RB_][4] = {};
#pragma unroll
    for (int kk = 0; kk < 32; ++kk) {
      int k = s * 32 + kk;
      float4 w = W2v[k * 64 + j4];
#pragma unroll
      for (int r = 0; r < RB_; ++r) {
        float x = sh1[r][k];
        a[r][0] = fmaf(x, w.x, a[r][0]);
        a[r][1] = fmaf(x, w.y, a[r][1]);
        a[r][2] = fmaf(x, w.z, a[r][2]);
        a[r][3] = fmaf(x, w.w, a[r][3]);
      }
    }
#pragma unroll
    for (int r = 0; r < RB_; ++r)
      *(float4*)&spool[(s * RB_ + r) * 256 + 4 * j4] =
          make_float4(a[r][0], a[r][1], a[r][2], a[r][3]);
  }
  __syncthreads();  // B4
  {
    int r = tid >> 8, j = tid & 255;
    float sum = bb2;
#pragma unroll
    for (int s = 0; s < 8; ++s) sum += spool[(s * RB_ + r) * 256 + j];
    sh2[r][j] = fmaxf(sum, 0.f);
  }
  __syncthreads();  // B5: sh2 ready, spool free

  // ---- layer 3: 256 -> 64. s3=tid>>4 (32 slices of 8 k), j4=tid&15;
  //      plus histogram atomics (independent work, overlaps) ----
  {
    const int s3 = tid >> 4, j4 = tid & 15;
    const float4* W3v = (const float4*)W3;
    float a[RB_][4] = {};
#pragma unroll
    for (int kk = 0; kk < 8; ++kk) {
      int k = s3 * 8 + kk;
      float4 w = W3v[k * 16 + j4];
#pragma unroll
      for (int r = 0; r < RB_; ++r) {
        float x = sh2[r][k];
        a[r][0] = fmaf(x, w.x, a[r][0]);
        a[r][1] = fmaf(x, w.y, a[r][1]);
        a[r][2] = fmaf(x, w.z, a[r][2]);
        a[r][3] = fmaf(x, w.w, a[r][3]);
      }
    }
#pragma unroll
    for (int r = 0; r < RB_; ++r)
      *(float4*)&spool[(s3 * RB_ + r) * 64 + 4 * j4] =
          make_float4(a[r][0], a[r][1], a[r][2], a[r][3]);
  }
  {
    int r = tid >> 8;
    float p0 = xn.x - eg.x;
    float p1 = xn.y - eg.y;
    float dist = sqrtf(p0 * p0 + p1 * p1);
    double angd = atan2((double)p0, (double)p1);
    if (angd < 0.0) angd += TWO_PI_D;
    float ang = (float)angd;
    int pidx = (int)(angd / (TWO_PI_D / (double)P_));
    bool mask = ((fabsf(p0) + fabsf(p1)) != 0.f) && (dist > 0.005f);
    if (mask && pidx >= 0 && pidx < P_) {
      atomicAdd(&cnt[r][pidx], 1.f);
      atomicAdd(&dsum[r][pidx], dist);
      atomicAdd(&asum[r][pidx], ang);
    }
  }
  __syncthreads();  // B6: layer3 partials + histogram done

  if (tid < RB_ * 64) {
    int r = tid >> 6, j = tid & 63;
    float sum = b3[j];
#pragma unroll
    for (int s = 0; s < 32; ++s) sum += spool[(s * RB_ + r) * 64 + j];
    f3s[r][j] = fmaxf(sum, 0.f);
  }
  __syncthreads();  // B7: f3s ready

  // ---- output: 2 rows x 1024 floats = 512 float4, 1 per thread ----
  {
    int r = tid >> 8, i4 = tid & 255;
    int p = i4 >> 5;
    int c0 = (i4 & 31) * 4;
    float nn = cnt[r][p] + EPS_F;
    float4 v;
    if (c0 < 64) {
      float sc = cnt[r][p] / nn;
      v = make_float4(f3s[r][c0 + 0] * sc, f3s[r][c0 + 1] * sc,
                      f3s[r][c0 + 2] * sc, f3s[r][c0 + 3] * sc);
    } else {
      int jj = c0 - 64;
      float dm = dsum[r][p] / nn;
      float am = asum[r][p] / nn;
      v.x = fmaxf(fmaf(dm, Wce[jj + 0], fmaf(am, Wce[64 + jj + 0], bce[jj + 0])), 0.f);
      v.y = fmaxf(fmaf(dm, Wce[jj + 1], fmaf(am, Wce[64 + jj + 1], bce[jj + 1])), 0.f);
      v.z = fmaxf(fmaf(dm, Wce[jj + 2], fmaf(am, Wce[64 + jj + 2], bce[jj + 2])), 0.f);
      v.w = fmaxf(fmaf(dm, Wce[jj + 3], fmaf(am, Wce[64 + jj + 3], bce[jj + 3])), 0.f);
    }
    *(float4*)(out + (size_t)(row0 + r) * 1024 + 4 * i4) = v;
  }
}

// ---------------------------------------------------------------------------
extern "C" void kernel_launch(void* const* d_in, const int* in_sizes, int n_in,
                              void* d_out, int out_size, void* d_ws,
                              size_t ws_size, hipStream_t stream) {
  const float* x_ego = (const float*)d_in[0];   // (32,50,2)
  const float* x_nei = (const float*)d_in[1];   // (32,256,50,2)
  const float* f_ego = (const float*)d_in[2];   // (32,25,128)
  const float* f_nei = (const float*)d_in[3];   // (32,256,25,128)
  const float* W1 = (const float*)d_in[4];      // (128,256)
  const float* b1 = (const float*)d_in[5];
  const float* W2 = (const float*)d_in[6];      // (256,256)
  const float* b2 = (const float*)d_in[7];
  const float* W3 = (const float*)d_in[8];      // (256,64)
  const float* b3 = (const float*)d_in[9];
  const float* Wce = (const float*)d_in[10];    // (2,64)
  const float* bce = (const float*)d_in[11];
  float* out = (float*)d_out;                   // (32,25,8,128)

  float* part = (float*)d_ws;  // 512 * 3200 floats = 6.55 MB

  k1_partial<<<B_ * NCH_, 800, 0, stream>>>(f_ego, f_nei, part);
  k2_fused<<<(B_ * T_S_) / RB_, 512, 0, stream>>>(part, W1, b1, W2, b2, W3,
                                                  b3, x_ego, x_nei, Wce, bce,
                                                  out);
}

// Round 8
// 34.015 us; speedup vs baseline: 4.7985x; 1.1525x over previous
//
#include <hip/hip_runtime.h>
#include <math.h>
#include <float.h>

#define B_ 32
#define N_ 256
#define T_OBS_ 50
#define T_S_ 25
#define D_ 128
#define D_H_ 256
#define P_ 8
#define PLANE_ (T_S_ * D_)  // 3200 floats per (b,n)
#define TG_ 13              // t-pair groups per batch (12 pairs + clamped last)

static constexpr double TWO_PI_D = 6.283185307179586476925286766559;
static constexpr float EPS_F = 1e-4f;

// ---------------------------------------------------------------------------
// Single fused kernel, dependency-free: block = (batch b, t-pair g).
// Phase A: stream f_nei[b, :, {t0,t1}, :] (256 n x 1 KB contiguous chunks,
//          L3-resident), max-reduce over n via 8 n-groups + LDS combine.
// Phase B: R5's float4 RB2 MLP + histogram + output for the two rows.
// Last group (g=12) clamps both rows to t=24: identical double-writes, benign.
// 416 blocks x 512 threads.
// ---------------------------------------------------------------------------
__global__ __launch_bounds__(512) void fused(
    const float* __restrict__ f_ego, const float* __restrict__ f_nei,
    const float* __restrict__ W1, const float* __restrict__ b1,
    const float* __restrict__ W2, const float* __restrict__ b2,
    const float* __restrict__ W3, const float* __restrict__ b3,
    const float* __restrict__ x_ego, const float* __restrict__ x_nei,
    const float* __restrict__ Wce, const float* __restrict__ bce,
    float* __restrict__ out) {
  __shared__ float spool[4096];   // 16 KB: n-max partials, then k-slice pool
  __shared__ float sin_[2][D_];   // 1 KB
  __shared__ float sh1[2][D_H_];  // 2 KB
  __shared__ float sh2[2][D_H_];  // 2 KB
  __shared__ float f3s[2][64];
  __shared__ float cnt[2][P_], dsum[2][P_], asum[2][P_];

  const int tid = threadIdx.x;
  const int b = blockIdx.x / TG_;
  const int g = blockIdx.x - b * TG_;
  const int t0 = 2 * g;
  const int t1 = (2 * g + 1 < T_S_) ? (2 * g + 1) : (T_S_ - 1);

  // ---- phase A: stream & partial-max. thread = (ng = tid>>6, sub = tid&63);
  //      sub -> (lt = sub>>5, d4 = sub&31); n = ng + 8*i, i = 0..31 ----
  {
    const int sub = tid & 63;
    const int lt = sub >> 5;
    const int d4 = sub & 31;
    const int ng = tid >> 6;
    const int t = lt ? t1 : t0;
    const float4 e =
        *(const float4*)(f_ego + ((size_t)b * T_S_ + t) * D_ + 4 * d4);
    const float* base = f_nei + (size_t)b * N_ * PLANE_ + t * D_ + 4 * d4;
    float4 m = make_float4(-FLT_MAX, -FLT_MAX, -FLT_MAX, -FLT_MAX);
#pragma unroll 8
    for (int i = 0; i < 32; ++i) {
      int n = ng + 8 * i;
      float4 v = *(const float4*)(base + (size_t)n * PLANE_);
      m.x = fmaxf(m.x, e.x * v.x);
      m.y = fmaxf(m.y, e.y * v.y);
      m.z = fmaxf(m.z, e.z * v.z);
      m.w = fmaxf(m.w, e.w * v.w);
    }
    ((float4*)spool)[ng * 64 + sub] = m;  // part[ng][sub]
  }

  if (tid < 2 * P_) {
    (&cnt[0][0])[tid] = 0.f;
    (&dsum[0][0])[tid] = 0.f;
    (&asum[0][0])[tid] = 0.f;
  }

  // ---- histogram input loads (independent; hide under combine) ----
  float2 eg, xn;
  {
    int r = tid >> 8, n = tid & 255;
    int t = r ? t1 : t0;
    int tobs = 2 * t;
    eg = *(const float2*)&x_ego[((size_t)b * T_OBS_ + tobs) * 2];
    xn = *(const float2*)&x_nei[(((size_t)b * N_ + n) * T_OBS_ + tobs) * 2];
  }
  const float bb1 = b1[tid & 255];
  const float bb2 = b2[tid & 255];

  __syncthreads();  // A-parts complete

  // ---- combine 8 n-group partials -> sin_ (64 threads, 1 float4 each) ----
  if (tid < 64) {
    float4 r = ((float4*)spool)[tid];
#pragma unroll
    for (int ngg = 1; ngg < 8; ++ngg) {
      float4 v = ((float4*)spool)[ngg * 64 + tid];
      r.x = fmaxf(r.x, v.x);
      r.y = fmaxf(r.y, v.y);
      r.z = fmaxf(r.z, v.z);
      r.w = fmaxf(r.w, v.w);
    }
    *(float4*)&sin_[tid >> 5][4 * (tid & 31)] = r;
  }
  __syncthreads();  // B1: sin_ ready, spool free

  // ---- layer 1: 128 -> 256. s=tid>>6 (8 slices of 16 k), j4=tid&63 ----
  {
    const int s = tid >> 6, j4 = tid & 63;
    const float4* W1v = (const float4*)W1;
    float a[2][4] = {};
#pragma unroll
    for (int kk = 0; kk < 16; ++kk) {
      int k = s * 16 + kk;
      float4 w = W1v[k * 64 + j4];
#pragma unroll
      for (int r = 0; r < 2; ++r) {
        float x = sin_[r][k];
        a[r][0] = fmaf(x, w.x, a[r][0]);
        a[r][1] = fmaf(x, w.y, a[r][1]);
        a[r][2] = fmaf(x, w.z, a[r][2]);
        a[r][3] = fmaf(x, w.w, a[r][3]);
      }
    }
#pragma unroll
    for (int r = 0; r < 2; ++r)
      *(float4*)&spool[(s * 2 + r) * 256 + 4 * j4] =
          make_float4(a[r][0], a[r][1], a[r][2], a[r][3]);
  }
  __syncthreads();  // B2
  {
    int r = tid >> 8, j = tid & 255;
    float sum = bb1;
#pragma unroll
    for (int s = 0; s < 8; ++s) sum += spool[(s * 2 + r) * 256 + j];
    sh1[r][j] = fmaxf(sum, 0.f);
  }
  __syncthreads();  // B3: sh1 ready

  // ---- layer 2: 256 -> 256. 8 slices of 32 k ----
  {
    const int s = tid >> 6, j4 = tid & 63;
    const float4* W2v = (const float4*)W2;
    float a[2][4] = {};
#pragma unroll
    for (int kk = 0; kk < 32; ++kk) {
      int k = s * 32 + kk;
      float4 w = W2v[k * 64 + j4];
#pragma unroll
      for (int r = 0; r < 2; ++r) {
        float x = sh1[r][k];
        a[r][0] = fmaf(x, w.x, a[r][0]);
        a[r][1] = fmaf(x, w.y, a[r][1]);
        a[r][2] = fmaf(x, w.z, a[r][2]);
        a[r][3] = fmaf(x, w.w, a[r][3]);
      }
    }
#pragma unroll
    for (int r = 0; r < 2; ++r)
      *(float4*)&spool[(s * 2 + r) * 256 + 4 * j4] =
          make_float4(a[r][0], a[r][1], a[r][2], a[r][3]);
  }
  __syncthreads();  // B4
  {
    int r = tid >> 8, j = tid & 255;
    float sum = bb2;
#pragma unroll
    for (int s = 0; s < 8; ++s) sum += spool[(s * 2 + r) * 256 + j];
    sh2[r][j] = fmaxf(sum, 0.f);
  }
  __syncthreads();  // B5: sh2 ready, spool free

  // ---- layer 3: 256 -> 64. s3=tid>>4 (32 slices of 8 k), j4=tid&15;
  //      plus histogram atomics (independent, overlaps) ----
  {
    const int s3 = tid >> 4, j4 = tid & 15;
    const float4* W3v = (const float4*)W3;
    float a[2][4] = {};
#pragma unroll
    for (int kk = 0; kk < 8; ++kk) {
      int k = s3 * 8 + kk;
      float4 w = W3v[k * 16 + j4];
#pragma unroll
      for (int r = 0; r < 2; ++r) {
        float x = sh2[r][k];
        a[r][0] = fmaf(x, w.x, a[r][0]);
        a[r][1] = fmaf(x, w.y, a[r][1]);
        a[r][2] = fmaf(x, w.z, a[r][2]);
        a[r][3] = fmaf(x, w.w, a[r][3]);
      }
    }
#pragma unroll
    for (int r = 0; r < 2; ++r)
      *(float4*)&spool[(s3 * 2 + r) * 64 + 4 * j4] =
          make_float4(a[r][0], a[r][1], a[r][2], a[r][3]);
  }
  {
    int r = tid >> 8;
    float p0 = xn.x - eg.x;
    float p1 = xn.y - eg.y;
    float dist = sqrtf(p0 * p0 + p1 * p1);
    double angd = atan2((double)p0, (double)p1);
    if (angd < 0.0) angd += TWO_PI_D;
    float ang = (float)angd;
    int pidx = (int)(angd / (TWO_PI_D / (double)P_));
    bool mask = ((fabsf(p0) + fabsf(p1)) != 0.f) && (dist > 0.005f);
    if (mask && pidx >= 0 && pidx < P_) {
      atomicAdd(&cnt[r][pidx], 1.f);
      atomicAdd(&dsum[r][pidx], dist);
      atomicAdd(&asum[r][pidx], ang);
    }
  }
  __syncthreads();  // B6: layer3 partials + histogram done

  if (tid < 2 * 64) {
    int r = tid >> 6, j = tid & 63;
    float sum = b3[j];
#pragma unroll
    for (int s = 0; s < 32; ++s) sum += spool[(s * 2 + r) * 64 + j];
    f3s[r][j] = fmaxf(sum, 0.f);
  }
  __syncthreads();  // B7: f3s ready

  // ---- output: 2 rows x 1024 floats = 512 float4, 1 per thread ----
  {
    int r = tid >> 8, i4 = tid & 255;
    int t = r ? t1 : t0;
    int p = i4 >> 5;
    int c0 = (i4 & 31) * 4;
    float nn = cnt[r][p] + EPS_F;
    float4 v;
    if (c0 < 64) {
      float sc = cnt[r][p] / nn;
      v = make_float4(f3s[r][c0 + 0] * sc, f3s[r][c0 + 1] * sc,
                      f3s[r][c0 + 2] * sc, f3s[r][c0 + 3] * sc);
    } else {
      int jj = c0 - 64;
      float dm = dsum[r][p] / nn;
      float am = asum[r][p] / nn;
      v.x = fmaxf(fmaf(dm, Wce[jj + 0], fmaf(am, Wce[64 + jj + 0], bce[jj + 0])), 0.f);
      v.y = fmaxf(fmaf(dm, Wce[jj + 1], fmaf(am, Wce[64 + jj + 1], bce[jj + 1])), 0.f);
      v.z = fmaxf(fmaf(dm, Wce[jj + 2], fmaf(am, Wce[64 + jj + 2], bce[jj + 2])), 0.f);
      v.w = fmaxf(fmaf(dm, Wce[jj + 3], fmaf(am, Wce[64 + jj + 3], bce[jj + 3])), 0.f);
    }
    *(float4*)(out + ((size_t)b * T_S_ + t) * 1024 + 4 * i4) = v;
  }
}

// ---------------------------------------------------------------------------
extern "C" void kernel_launch(void* const* d_in, const int* in_sizes, int n_in,
                              void* d_out, int out_size, void* d_ws,
                              size_t ws_size, hipStream_t stream) {
  const float* x_ego = (const float*)d_in[0];   // (32,50,2)
  const float* x_nei = (const float*)d_in[1];   // (32,256,50,2)
  const float* f_ego = (const float*)d_in[2];   // (32,25,128)
  const float* f_nei = (const float*)d_in[3];   // (32,256,25,128)
  const float* W1 = (const float*)d_in[4];      // (128,256)
  const float* b1 = (const float*)d_in[5];
  const float* W2 = (const float*)d_in[6];      // (256,256)
  const float* b2 = (const float*)d_in[7];
  const float* W3 = (const float*)d_in[8];      // (256,64)
  const float* b3 = (const float*)d_in[9];
  const float* Wce = (const float*)d_in[10];    // (2,64)
  const float* bce = (const float*)d_in[11];
  float* out = (float*)d_out;                   // (32,25,8,128)

  fused<<<B_ * TG_, 512, 0, stream>>>(f_ego, f_nei, W1, b1, W2, b2, W3, b3,
                                      x_ego, x_nei, Wce, bce, out);
}